// Round 3
// baseline (325.771 us; speedup 1.0000x reference)
//
#include <hip/hip_runtime.h>
#include <stdint.h>

#define DD 512
#define MTOT 32768  // B*N = 8*4096

typedef float f32x4 __attribute__((ext_vector_type(4)));
typedef __bf16 bf16x8 __attribute__((ext_vector_type(8)));

static __device__ __forceinline__ unsigned short f2bf(float f) {
  union { float f; unsigned int u; } c; c.f = f;
  unsigned int r = c.u + 0x7fffu + ((c.u >> 16) & 1u);
  return (unsigned short)(r >> 16);
}
static __device__ __forceinline__ float bf2f(unsigned short h) {
  union { unsigned int u; float f; } c; c.u = ((unsigned int)h) << 16;
  return c.f;
}

union FragU { uint4 u; bf16x8 b; };

static __device__ __forceinline__ void load_lds16(const void* g, void* l) {
  __builtin_amdgcn_global_load_lds(
      (const __attribute__((address_space(1))) void*)g,
      (__attribute__((address_space(3))) void*)l, 16, 0, 0);
}

// ---------------- mega conversion kernel (one launch) ---------------------
// gx [0,768):    Wq/Wk/Wf -> bf16 (256 blocks each, 4 elems/thread)
// gx [768,868):  zero stats region (ssqQ, ssqK, Pd, G) = 102400 floats
// gx [868,2916): a/b -> bf16, grid-stride: 1024 blocks per tensor,
//                8 iterations x 8 elems/thread (16 dwordx4 loads in flight)
__global__ __launch_bounds__(256) void cvt_all_k(
    const float* __restrict__ a, const float* __restrict__ b,
    const float* __restrict__ W0, const float* __restrict__ W1,
    const float* __restrict__ W2,
    unsigned short* __restrict__ da, unsigned short* __restrict__ db,
    unsigned short* __restrict__ D0, unsigned short* __restrict__ D1,
    unsigned short* __restrict__ D2, float* __restrict__ stats) {
  const int gx = blockIdx.x, tid = threadIdx.x;
  if (gx < 768) {
    int slab = gx >> 8;
    int off = ((gx & 255) * 256 + tid) * 4;
    const float* s = slab == 0 ? W0 : slab == 1 ? W1 : W2;
    unsigned short* d = slab == 0 ? D0 : slab == 1 ? D1 : D2;
    float4 f = *(const float4*)(s + off);
    ushort4 h;
    h.x = f2bf(f.x); h.y = f2bf(f.y); h.z = f2bf(f.z); h.w = f2bf(f.w);
    *(ushort4*)(d + off) = h;
  } else if (gx < 868) {
    int i = ((gx - 768) * 256 + tid) * 4;  // [0, 102400)
    *(float4*)(stats + i) = make_float4(0.f, 0.f, 0.f, 0.f);
  } else {
    const int u = gx - 868;                 // [0, 2048)
    const float* s = (u >> 10) ? b : a;
    unsigned short* d = (u >> 10) ? db : da;
    const size_t base = ((size_t)(u & 1023) * 256 + tid) * 8;
#pragma unroll
    for (int t = 0; t < 8; t++) {
      size_t i = base + (size_t)t * 2097152;  // 1024 blk * 256 thr * 8 elems
      f32x4 f0 = *(const f32x4*)(s + i);
      f32x4 f1 = *(const f32x4*)(s + i + 4);
      union { uint4 u4; unsigned short h[8]; } pk;
      pk.h[0] = f2bf(f0.x); pk.h[1] = f2bf(f0.y);
      pk.h[2] = f2bf(f0.z); pk.h[3] = f2bf(f0.w);
      pk.h[4] = f2bf(f1.x); pk.h[5] = f2bf(f1.y);
      pk.h[6] = f2bf(f1.z); pk.h[7] = f2bf(f1.w);
      *(uint4*)(d + i) = pk.u4;
    }
  }
}

// ---------------- W'p[b] = Wp * G[b,:] (broadcast over rows) --------------
__global__ __launch_bounds__(256) void scalew_k(const float* __restrict__ Wp,
    const float* __restrict__ G, unsigned short* __restrict__ out) {
  int i = (blockIdx.x * 256 + threadIdx.x) * 4;  // [0, 8*262144)
  int b = i >> 18;
  int rem = i & 262143;
  int d = rem & 511;
  float4 w = *(const float4*)(Wp + rem);
  float4 g = *(const float4*)(G + b * DD + d);
  ushort4 h;
  h.x = f2bf(w.x * g.x); h.y = f2bf(w.y * g.y);
  h.z = f2bf(w.z * g.z); h.w = f2bf(w.w * g.w);
  *(ushort4*)(out + i) = h;
}

// ---------------- shared GEMM core: 128x128 tile, BK=64, m97 structure ----
// global_load_lds width-16 staging, XOR-swizzled LDS (kseg ^ (row&7)).
static __device__ __forceinline__ void gemm_core(
    const unsigned short* __restrict__ X, const unsigned short* __restrict__ W,
    int row0, int col0, unsigned short* As, unsigned short* Bs,
    f32x4 (&acc)[4][4]) {
  const int tid = threadIdx.x;
  const int lane = tid & 63, wave = tid >> 6;
  const int sr = lane >> 3;
  const int scol = ((lane & 7) ^ sr) * 8;
  const unsigned short* Ag = X + (size_t)(row0 + wave * 32 + sr) * DD + scol;
  const unsigned short* Bg = W + (size_t)(col0 + wave * 32 + sr) * DD + scol;
  const int ldsb = wave * 32 * 64;
  const int fr = lane & 15, quad = lane >> 4;
  const int wr = (wave >> 1) * 64, wc = (wave & 1) * 64;
  const int sw0 = ((quad ^ (fr & 7)) * 8);
  const int sw1 = (((quad + 4) ^ (fr & 7)) * 8);

  for (int k0 = 0; k0 < DD; k0 += 64) {
#pragma unroll
    for (int q = 0; q < 4; q++) {
      load_lds16(Ag + (size_t)q * 8 * DD + k0, As + ldsb + q * 8 * 64);
      load_lds16(Bg + (size_t)q * 8 * DD + k0, Bs + ldsb + q * 8 * 64);
    }
    __syncthreads();
#pragma unroll
    for (int kk = 0; kk < 2; kk++) {
      const int sw = kk ? sw1 : sw0;
      bf16x8 af[4], bfr[4];
#pragma unroll
      for (int i = 0; i < 4; i++) {
        FragU u; u.u = *(const uint4*)&As[(wr + i * 16 + fr) * 64 + sw];
        af[i] = u.b;
      }
#pragma unroll
      for (int j = 0; j < 4; j++) {
        FragU u; u.u = *(const uint4*)&Bs[(wc + j * 16 + fr) * 64 + sw];
        bfr[j] = u.b;
      }
#pragma unroll
      for (int i = 0; i < 4; i++)
#pragma unroll
        for (int j = 0; j < 4; j++)
          acc[i][j] = __builtin_amdgcn_mfma_f32_16x16x32_bf16(af[i], bfr[j], acc[i][j], 0, 0, 0);
    }
    __syncthreads();
  }
}

// --------- merged Q/K GEMM: blocks [0,256) = Q, [256,512) = K -------------
// Q: C = a*Wq^T + bq -> bf16, row ssq + wg-dot atomics
// K: C = b*Wk^T + bk -> bf16, row ssq atomics
__global__ __launch_bounds__(256) void gemm_qk_k(
    const unsigned short* __restrict__ Xq, const unsigned short* __restrict__ Xk,
    const unsigned short* __restrict__ Wqw, const unsigned short* __restrict__ Wkw,
    const float* __restrict__ bq, const float* __restrict__ bk,
    const float* __restrict__ wg,
    float* __restrict__ ssqQ, float* __restrict__ ssqK, float* __restrict__ Pdot,
    unsigned short* __restrict__ Cq, unsigned short* __restrict__ Ck) {
  __shared__ unsigned short As[128 * 64];
  __shared__ unsigned short Bs[128 * 64];
  const int isK = blockIdx.x >> 8;
  const int row0 = (blockIdx.x & 255) * 128, col0 = blockIdx.y * 128;
  const unsigned short* X = isK ? Xk : Xq;
  const unsigned short* W = isK ? Wkw : Wqw;
  const float* bias = isK ? bk : bq;
  float* ssq = isK ? ssqK : ssqQ;
  unsigned short* C = isK ? Ck : Cq;

  f32x4 acc[4][4] = {};
  gemm_core(X, W, row0, col0, As, Bs, acc);

  const int lane = threadIdx.x & 63, wave = threadIdx.x >> 6;
  const int fr = lane & 15, quad = lane >> 4;
  const int wr = (wave >> 1) * 64, wc = (wave & 1) * 64;
  const int colbase = col0 + wc + fr;
  float bv4[4], wg4[4];
#pragma unroll
  for (int j = 0; j < 4; j++) bv4[j] = bias[colbase + j * 16];
  if (!isK) {
#pragma unroll
    for (int j = 0; j < 4; j++) wg4[j] = wg[colbase + j * 16];
  }
#pragma unroll
  for (int i = 0; i < 4; i++) {
#pragma unroll
    for (int r = 0; r < 4; r++) {
      const int row = row0 + wr + i * 16 + quad * 4 + r;
      float ssum = 0.f, dsum = 0.f;
#pragma unroll
      for (int j = 0; j < 4; j++) {
        size_t idx = (size_t)row * DD + colbase + j * 16;
        float v = acc[i][j][r] + bv4[j];
        C[idx] = f2bf(v);
        ssum += v * v;
        if (!isK) dsum += v * wg4[j];
      }
#pragma unroll
      for (int m = 1; m < 16; m <<= 1) ssum += __shfl_xor(ssum, m, 64);
      if (!isK) {
#pragma unroll
        for (int m = 1; m < 16; m <<= 1) dsum += __shfl_xor(dsum, m, 64);
      }
      if (fr == 0) {
        atomicAdd(&ssq[row], ssum);
        if (!isK) atomicAdd(&Pdot[row], dsum);
      }
    }
  }
}

// ---------------- GEMM with scalar-folded epilogues -----------------------
// EMODE 3: kinv*acc + bias + qinv*Qadd -> bf16 (P GEMM, per-batch W)
// EMODE 4: acc + bias -> fp32 (final GEMM)
template<int BBATCH, int EMODE>
__global__ __launch_bounds__(256) void gemm_k(
    const unsigned short* __restrict__ X,
    const unsigned short* __restrict__ Wb,
    const float* __restrict__ bias,
    const unsigned short* __restrict__ Qadd,
    const float* __restrict__ qinv,
    const float* __restrict__ kinv,
    void* __restrict__ Cv) {
  __shared__ unsigned short As[128 * 64];
  __shared__ unsigned short Bs[128 * 64];
  const int row0 = blockIdx.x * 128, col0 = blockIdx.y * 128;
  const unsigned short* W = Wb + (BBATCH ? (size_t)(row0 >> 12) * 262144 : 0);

  f32x4 acc[4][4] = {};
  gemm_core(X, W, row0, col0, As, Bs, acc);

  const int lane = threadIdx.x & 63, wave = threadIdx.x >> 6;
  const int fr = lane & 15, quad = lane >> 4;
  const int wr = (wave >> 1) * 64, wc = (wave & 1) * 64;
  const int colbase = col0 + wc + fr;
  float bv4[4];
#pragma unroll
  for (int j = 0; j < 4; j++) bv4[j] = bias[colbase + j * 16];
#pragma unroll
  for (int i = 0; i < 4; i++) {
#pragma unroll
    for (int r = 0; r < 4; r++) {
      const int row = row0 + wr + i * 16 + quad * 4 + r;
      float ki = 1.f, qi = 1.f;
      if (EMODE == 3) { ki = kinv[row]; qi = qinv[row]; }
#pragma unroll
      for (int j = 0; j < 4; j++) {
        size_t idx = (size_t)row * DD + colbase + j * 16;
        if (EMODE == 3) {
          float v = acc[i][j][r] * ki + bv4[j] + qi * bf2f(Qadd[idx]);
          ((unsigned short*)Cv)[idx] = f2bf(v);
        } else {
          ((float*)Cv)[idx] = acc[i][j][r] + bv4[j];
        }
      }
    }
  }
}

// ------- merged finstat+pool: per block (b, chunk of 128 rows) ------------
// Phase A: recompute batch-b sinv from ssqQ/Pd (L2-resident, 32x redundant);
//          write qinv/kinv for own 128 rows.
// Phase B: G[b,:] += sum_r (P*qinv^2*sinv) * Qraw[r,:], vectorized loads.
__global__ __launch_bounds__(256) void pool2_k(
    const float* __restrict__ ssqQ, const float* __restrict__ ssqK,
    const float* __restrict__ P, float* __restrict__ qinv,
    float* __restrict__ kinv, const unsigned short* __restrict__ Q,
    float* __restrict__ G) {
  const int b = blockIdx.x >> 5, chunk = blockIdx.x & 31;
  const int t = threadIdx.x, lane = t & 63, wave = t >> 6;
  __shared__ float sred[4];
  __shared__ float gred[4][512];

  float ss = 0.f;
  for (int i = t; i < 4096; i += 256) {
    int n = b * 4096 + i;
    float qi = 1.0f / fmaxf(sqrtf(ssqQ[n]), 1e-12f);
    float A = P[n] * qi;
    ss += A * A;
  }
#pragma unroll
  for (int m = 1; m < 64; m <<= 1) ss += __shfl_xor(ss, m, 64);
  if (lane == 0) sred[wave] = ss;
  if (t < 128) {
    int n = b * 4096 + chunk * 128 + t;
    qinv[n] = 1.0f / fmaxf(sqrtf(ssqQ[n]), 1e-12f);
    kinv[n] = 1.0f / fmaxf(sqrtf(ssqK[n]), 1e-12f);
  }
  __syncthreads();
  const float sinv_b =
      1.0f / fmaxf(sqrtf(sred[0] + sred[1] + sred[2] + sred[3]), 1e-12f);

  float acc[8] = {};
  const int r0 = b * 4096 + chunk * 128 + wave * 32;
  for (int r = 0; r < 32; r++) {
    const int n = r0 + r;
    float qi = 1.0f / fmaxf(sqrtf(ssqQ[n]), 1e-12f);
    float wrow = P[n] * qi * qi * sinv_b;
    uint4 u = *(const uint4*)(Q + (size_t)n * DD + lane * 8);
    const unsigned short* h = (const unsigned short*)&u;
#pragma unroll
    for (int j = 0; j < 8; j++) acc[j] += wrow * bf2f(h[j]);
  }
#pragma unroll
  for (int j = 0; j < 8; j++) gred[wave][lane * 8 + j] = acc[j];
  __syncthreads();
  float g0 = gred[0][t] + gred[1][t] + gred[2][t] + gred[3][t];
  float g1 = gred[0][t + 256] + gred[1][t + 256] + gred[2][t + 256] + gred[3][t + 256];
  atomicAdd(&G[b * DD + t], g0);
  atomicAdd(&G[b * DD + t + 256], g1);
}

extern "C" void kernel_launch(void* const* d_in, const int* in_sizes, int n_in,
                              void* d_out, int out_size, void* d_ws, size_t ws_size,
                              hipStream_t stream) {
  const float* a   = (const float*)d_in[0];
  const float* b   = (const float*)d_in[1];
  const float* Wq  = (const float*)d_in[2];
  const float* bq  = (const float*)d_in[3];
  const float* Wk  = (const float*)d_in[4];
  const float* bk  = (const float*)d_in[5];
  const float* wg  = (const float*)d_in[6];
  const float* Wp  = (const float*)d_in[7];
  const float* bp  = (const float*)d_in[8];
  const float* Wf  = (const float*)d_in[9];
  const float* bfb = (const float*)d_in[10];

  const size_t WELEM = 262144;          // 512*512
  const size_t MD = (size_t)MTOT * DD;  // 16,777,216 elems

  unsigned short* B0 = (unsigned short*)d_ws;   // a(bf16) -> O1
  unsigned short* B1 = B0 + MD;                 // b(bf16)
  unsigned short* B2 = B1 + MD;                 // Q raw
  unsigned short* B3 = B2 + MD;                 // K raw
  unsigned short* Wqb = B3 + MD;
  unsigned short* Wkb = Wqb + WELEM;
  unsigned short* Wfb = Wkb + WELEM;
  unsigned short* Wps = Wfb + WELEM;            // 8 * 262144 per-batch scaled Wp
  float* stats = (float*)(Wps + 8 * WELEM);
  float* ssqQ  = stats;                 // [MTOT]   zeroed by cvt_all_k
  float* ssqK  = stats + MTOT;          // [MTOT]   zeroed by cvt_all_k
  float* Pd    = stats + 2 * MTOT;      // [MTOT]   zeroed by cvt_all_k
  float* G     = stats + 3 * MTOT;      // [8*512]  zeroed by cvt_all_k
  float* qinv  = G + 4096;
  float* kinv  = qinv + MTOT;

  // a->B0, b->B1, weights->bf16, zero stats+G   (one launch)
  cvt_all_k<<<dim3(2916), dim3(256), 0, stream>>>(
      a, b, Wq, Wk, Wf, B0, B1, Wqb, Wkb, Wfb, stats);
  // Q = a*Wq^T+bq -> B2 (+ssqQ, Pdot); K = b*Wk^T+bk -> B3 (+ssqK)
  gemm_qk_k<<<dim3(512, 4), dim3(256), 0, stream>>>(
      B0, B1, Wqb, Wkb, bq, bk, wg, ssqQ, ssqK, Pd, B2, B3);
  // qinv/kinv + per-batch sinv + learned pooling -> G
  pool2_k<<<dim3(256), dim3(256), 0, stream>>>(ssqQ, ssqK, Pd, qinv, kinv, B2, G);
  // fold G into Wp per batch
  scalew_k<<<dim3(2048), dim3(256), 0, stream>>>(Wp, G, Wps);
  // O1 = kinv*(Kraw*(Wp.G)^T) + bp + qinv*Qraw -> B0
  gemm_k<1, 3><<<dim3(256, 4), dim3(256), 0, stream>>>(
      B3, Wps, bp, B2, qinv, kinv, B0);
  // out = O1*Wf^T + bf (fp32)
  gemm_k<0, 4><<<dim3(256, 4), dim3(256), 0, stream>>>(
      B0, Wfb, bfb, nullptr, nullptr, nullptr, d_out);
}

// Round 4
// 307.980 us; speedup vs baseline: 1.0578x; 1.0578x over previous
//
#include <hip/hip_runtime.h>
#include <stdint.h>

#define DD 512
#define MTOT 32768  // B*N = 8*4096

typedef float f32x4 __attribute__((ext_vector_type(4)));
typedef __bf16 bf16x8 __attribute__((ext_vector_type(8)));

static __device__ __forceinline__ unsigned short f2bf(float f) {
  union { float f; unsigned int u; } c; c.f = f;
  unsigned int r = c.u + 0x7fffu + ((c.u >> 16) & 1u);
  return (unsigned short)(r >> 16);
}
static __device__ __forceinline__ float bf2f(unsigned short h) {
  union { unsigned int u; float f; } c; c.u = ((unsigned int)h) << 16;
  return c.f;
}

union FragU { uint4 u; bf16x8 b; };

static __device__ __forceinline__ void load_lds16(const void* g, void* l) {
  __builtin_amdgcn_global_load_lds(
      (const __attribute__((address_space(1))) void*)g,
      (__attribute__((address_space(3))) void*)l, 16, 0, 0);
}

// ---- three 512x512 weights -> bf16, plus zeroing of the stats buffers ----
// blocks [0,768): weight cvt. blocks [768,868): zero stats (3*MTOT + 4096).
__global__ __launch_bounds__(256) void cvt3w_k(const float* __restrict__ W0,
    const float* __restrict__ W1, const float* __restrict__ W2,
    unsigned short* __restrict__ D0, unsigned short* __restrict__ D1,
    unsigned short* __restrict__ D2, float* __restrict__ stats) {
  int slab = blockIdx.x >> 8;
  if (slab == 3) {
    int i = ((blockIdx.x - 768) * 256 + threadIdx.x) * 4;  // [0, 102400)
    *(float4*)(stats + i) = make_float4(0.f, 0.f, 0.f, 0.f);
    return;
  }
  int off = ((blockIdx.x & 255) * 256 + threadIdx.x) * 4;
  const float* s = slab == 0 ? W0 : slab == 1 ? W1 : W2;
  unsigned short* d = slab == 0 ? D0 : slab == 1 ? D1 : D2;
  float4 f = *(const float4*)(s + off);
  ushort4 h;
  h.x = f2bf(f.x); h.y = f2bf(f.y); h.z = f2bf(f.z); h.w = f2bf(f.w);
  *(ushort4*)(d + off) = h;
}

// ---------------- W'p[b] = Wp * G[b,:] (broadcast over rows) --------------
__global__ __launch_bounds__(256) void scalew_k(const float* __restrict__ Wp,
    const float* __restrict__ G, unsigned short* __restrict__ out) {
  int i = (blockIdx.x * 256 + threadIdx.x) * 4;  // [0, 8*262144)
  int b = i >> 18;
  int rem = i & 262143;
  int d = rem & 511;
  float4 w = *(const float4*)(Wp + rem);
  float4 g = *(const float4*)(G + b * DD + d);
  ushort4 h;
  h.x = f2bf(w.x * g.x); h.y = f2bf(w.y * g.y);
  h.z = f2bf(w.z * g.z); h.w = f2bf(w.w * g.w);
  *(ushort4*)(out + i) = h;
}

// ---------------- shared bf16 GEMM core (m97 structure) -------------------
// 128x128 tile, BK=64, global_load_lds width-16, XOR-swizzle kseg^(row&7).
static __device__ __forceinline__ void gemm_core(
    const unsigned short* __restrict__ X, const unsigned short* __restrict__ W,
    int row0, int col0, unsigned short* As, unsigned short* Bs,
    f32x4 (&acc)[4][4]) {
  const int tid = threadIdx.x;
  const int lane = tid & 63, wave = tid >> 6;
  const int sr = lane >> 3;
  const int scol = ((lane & 7) ^ sr) * 8;
  const unsigned short* Ag = X + (size_t)(row0 + wave * 32 + sr) * DD + scol;
  const unsigned short* Bg = W + (size_t)(col0 + wave * 32 + sr) * DD + scol;
  const int ldsb = wave * 32 * 64;
  const int fr = lane & 15, quad = lane >> 4;
  const int wr = (wave >> 1) * 64, wc = (wave & 1) * 64;
  const int sw0 = ((quad ^ (fr & 7)) * 8);
  const int sw1 = (((quad + 4) ^ (fr & 7)) * 8);

  for (int k0 = 0; k0 < DD; k0 += 64) {
#pragma unroll
    for (int q = 0; q < 4; q++) {
      load_lds16(Ag + (size_t)q * 8 * DD + k0, As + ldsb + q * 8 * 64);
      load_lds16(Bg + (size_t)q * 8 * DD + k0, Bs + ldsb + q * 8 * 64);
    }
    __syncthreads();
#pragma unroll
    for (int kk = 0; kk < 2; kk++) {
      const int sw = kk ? sw1 : sw0;
      bf16x8 af[4], bfr[4];
#pragma unroll
      for (int i = 0; i < 4; i++) {
        FragU u; u.u = *(const uint4*)&As[(wr + i * 16 + fr) * 64 + sw];
        af[i] = u.b;
      }
#pragma unroll
      for (int j = 0; j < 4; j++) {
        FragU u; u.u = *(const uint4*)&Bs[(wc + j * 16 + fr) * 64 + sw];
        bfr[j] = u.b;
      }
#pragma unroll
      for (int i = 0; i < 4; i++)
#pragma unroll
        for (int j = 0; j < 4; j++)
          acc[i][j] = __builtin_amdgcn_mfma_f32_16x16x32_bf16(af[i], bfr[j], acc[i][j], 0, 0, 0);
    }
    __syncthreads();
  }
}

// --------- merged Q/K GEMM with fp32 A operand (fused conversion) ---------
// A staged into LDS as RAW fp32 via global_load_lds (async); converted to
// bf16 at frag-read time (2x ds_read_b128 + cvt). Granule swizzle:
// LDS[row][g_phys] holds logical granule g_phys ^ xorv(row&7), where
// xorv(r) = ((r&7)>>2) | ((r&3)<<1)  (bijective over 0..7, spreads the 8
// 16B-granule slots so 16-lane frag reads are <=2-way bank aliased).
// Swizzle applied on the per-lane GLOBAL source address; LDS dest linear.
// blocks: swz [0,1024) = Q (a*Wq^T+bq, +ssq +wg-dot), [1024,2048) = K.
// XCD-chunked: swz = (bid&7)*256 + bid>>3; col-major within row-tile.
__global__ __launch_bounds__(256) void gemm_qk_k(
    const float* __restrict__ Xa, const float* __restrict__ Xb,
    const unsigned short* __restrict__ Wqw, const unsigned short* __restrict__ Wkw,
    const float* __restrict__ bq, const float* __restrict__ bk,
    const float* __restrict__ wg,
    float* __restrict__ ssqQ, float* __restrict__ ssqK, float* __restrict__ Pdot,
    unsigned short* __restrict__ Cq, unsigned short* __restrict__ Ck) {
  __shared__ float AsF[128 * 64];          // 32 KB
  __shared__ unsigned short Bs[128 * 64];  // 16 KB
  const int swz = (blockIdx.x & 7) * 256 + (blockIdx.x >> 3);
  const int isK = swz >> 10;
  const int t = swz & 1023;
  const int row0 = (t >> 2) * 128, col0 = (t & 3) * 128;
  const float* X = isK ? Xb : Xa;
  const unsigned short* W = isK ? Wkw : Wqw;
  const float* bias = isK ? bk : bq;
  float* ssq = isK ? ssqK : ssqQ;
  unsigned short* C = isK ? Ck : Cq;

  const int lane = threadIdx.x & 63, wave = threadIdx.x >> 6;

  // ---- A staging (fp32): 8 instrs/K-step, 4 rows each ----
  const int rl = lane >> 4;                       // row within 4-row slab
  const int gsE = (lane & 15) ^ (rl << 1);        // source granule, even q
  const int gsO = gsE ^ 1;                        // source granule, odd q
  const float* AgE = X + (size_t)(row0 + wave * 32 + rl) * DD + gsE * 4;
  const float* AgO = X + (size_t)(row0 + wave * 32 + rl) * DD + gsO * 4;
  const int ldsA = wave * 2048;                   // float elems (32 rows x 64)

  // ---- B staging (bf16): as gemm_core ----
  const int sr = lane >> 3;
  const int scol = ((lane & 7) ^ sr) * 8;
  const unsigned short* Bg = W + (size_t)(col0 + wave * 32 + sr) * DD + scol;
  const int ldsb = wave * 32 * 64;

  const int fr = lane & 15, quad = lane >> 4;
  const int wr = (wave >> 1) * 64, wc = (wave & 1) * 64;
  const int xorv = ((fr & 7) >> 2) | ((fr & 3) << 1);
  const int swB0 = ((quad ^ (fr & 7)) * 8);
  const int swB1 = (((quad + 4) ^ (fr & 7)) * 8);

  f32x4 acc[4][4] = {};

  for (int k0 = 0; k0 < DD; k0 += 64) {
#pragma unroll
    for (int q = 0; q < 8; q++) {
      const float* src = ((q & 1) ? AgO : AgE) + (size_t)q * 4 * DD + k0;
      load_lds16(src, AsF + ldsA + q * 256);
    }
#pragma unroll
    for (int q = 0; q < 4; q++)
      load_lds16(Bg + (size_t)q * 8 * DD + k0, Bs + ldsb + q * 8 * 64);
    __syncthreads();
#pragma unroll
    for (int kk = 0; kk < 2; kk++) {
      const int glo = ((kk * 4 + quad) * 2) ^ xorv;  // phys granule, k 0-3
      const int ghi = glo ^ 1;                       // phys granule, k 4-7
      const int swB = kk ? swB1 : swB0;
      bf16x8 af[4], bfr[4];
#pragma unroll
      for (int i = 0; i < 4; i++) {
        const float* ap = &AsF[(wr + i * 16 + fr) * 64];
        f32x4 lo = *(const f32x4*)(ap + glo * 4);
        f32x4 hi = *(const f32x4*)(ap + ghi * 4);
        bf16x8 v;
        v[0] = (__bf16)lo.x; v[1] = (__bf16)lo.y;
        v[2] = (__bf16)lo.z; v[3] = (__bf16)lo.w;
        v[4] = (__bf16)hi.x; v[5] = (__bf16)hi.y;
        v[6] = (__bf16)hi.z; v[7] = (__bf16)hi.w;
        af[i] = v;
      }
#pragma unroll
      for (int j = 0; j < 4; j++) {
        FragU u; u.u = *(const uint4*)&Bs[(wc + j * 16 + fr) * 64 + swB];
        bfr[j] = u.b;
      }
#pragma unroll
      for (int i = 0; i < 4; i++)
#pragma unroll
        for (int j = 0; j < 4; j++)
          acc[i][j] = __builtin_amdgcn_mfma_f32_16x16x32_bf16(af[i], bfr[j], acc[i][j], 0, 0, 0);
    }
    __syncthreads();
  }

  // epilogue: C/D layout col=lane&15, row=(lane>>4)*4+reg
  const int colbase = col0 + wc + fr;
  float bv4[4], wg4[4];
#pragma unroll
  for (int j = 0; j < 4; j++) bv4[j] = bias[colbase + j * 16];
  if (!isK) {
#pragma unroll
    for (int j = 0; j < 4; j++) wg4[j] = wg[colbase + j * 16];
  }
#pragma unroll
  for (int i = 0; i < 4; i++) {
#pragma unroll
    for (int r = 0; r < 4; r++) {
      const int row = row0 + wr + i * 16 + quad * 4 + r;
      float ssum = 0.f, dsum = 0.f;
#pragma unroll
      for (int j = 0; j < 4; j++) {
        size_t idx = (size_t)row * DD + colbase + j * 16;
        float v = acc[i][j][r] + bv4[j];
        C[idx] = f2bf(v);
        ssum += v * v;
        if (!isK) dsum += v * wg4[j];
      }
#pragma unroll
      for (int m = 1; m < 16; m <<= 1) ssum += __shfl_xor(ssum, m, 64);
      if (!isK) {
#pragma unroll
        for (int m = 1; m < 16; m <<= 1) dsum += __shfl_xor(dsum, m, 64);
      }
      if (fr == 0) {
        atomicAdd(&ssq[row], ssum);
        if (!isK) atomicAdd(&Pdot[row], dsum);
      }
    }
  }
}

// ---------------- bf16 GEMM with scalar-folded epilogues ------------------
// EMODE 3: kinv*acc + bias + qinv*Qadd -> bf16 (P GEMM, per-batch W)
// EMODE 4: acc + bias -> fp32 (final GEMM)
// XCD-chunked swizzle, col-major within row-tile (1024 blocks).
template<int BBATCH, int EMODE>
__global__ __launch_bounds__(256) void gemm_k(
    const unsigned short* __restrict__ X,
    const unsigned short* __restrict__ Wb,
    const float* __restrict__ bias,
    const unsigned short* __restrict__ Qadd,
    const float* __restrict__ qinv,
    const float* __restrict__ kinv,
    void* __restrict__ Cv) {
  __shared__ unsigned short As[128 * 64];
  __shared__ unsigned short Bs[128 * 64];
  const int swz = (blockIdx.x & 7) * 128 + (blockIdx.x >> 3);
  const int row0 = (swz >> 2) * 128, col0 = (swz & 3) * 128;
  const unsigned short* W = Wb + (BBATCH ? (size_t)(row0 >> 12) * 262144 : 0);

  f32x4 acc[4][4] = {};
  gemm_core(X, W, row0, col0, As, Bs, acc);

  const int lane = threadIdx.x & 63, wave = threadIdx.x >> 6;
  const int fr = lane & 15, quad = lane >> 4;
  const int wr = (wave >> 1) * 64, wc = (wave & 1) * 64;
  const int colbase = col0 + wc + fr;
  float bv4[4];
#pragma unroll
  for (int j = 0; j < 4; j++) bv4[j] = bias[colbase + j * 16];
#pragma unroll
  for (int i = 0; i < 4; i++) {
#pragma unroll
    for (int r = 0; r < 4; r++) {
      const int row = row0 + wr + i * 16 + quad * 4 + r;
      float ki = 1.f, qi = 1.f;
      if (EMODE == 3) { ki = kinv[row]; qi = qinv[row]; }
#pragma unroll
      for (int j = 0; j < 4; j++) {
        size_t idx = (size_t)row * DD + colbase + j * 16;
        if (EMODE == 3) {
          float v = acc[i][j][r] * ki + bv4[j] + qi * bf2f(Qadd[idx]);
          ((unsigned short*)Cv)[idx] = f2bf(v);
        } else {
          ((float*)Cv)[idx] = acc[i][j][r] + bv4[j];
        }
      }
    }
  }
}

// ------- merged finstat+pool: per block (b, chunk of 128 rows) ------------
__global__ __launch_bounds__(256) void pool2_k(
    const float* __restrict__ ssqQ, const float* __restrict__ ssqK,
    const float* __restrict__ P, float* __restrict__ qinv,
    float* __restrict__ kinv, const unsigned short* __restrict__ Q,
    float* __restrict__ G) {
  const int b = blockIdx.x >> 5, chunk = blockIdx.x & 31;
  const int t = threadIdx.x, lane = t & 63, wave = t >> 6;
  __shared__ float sred[4];
  __shared__ float gred[4][512];

  float ss = 0.f;
  for (int i = t; i < 4096; i += 256) {
    int n = b * 4096 + i;
    float qi = 1.0f / fmaxf(sqrtf(ssqQ[n]), 1e-12f);
    float A = P[n] * qi;
    ss += A * A;
  }
#pragma unroll
  for (int m = 1; m < 64; m <<= 1) ss += __shfl_xor(ss, m, 64);
  if (lane == 0) sred[wave] = ss;
  if (t < 128) {
    int n = b * 4096 + chunk * 128 + t;
    qinv[n] = 1.0f / fmaxf(sqrtf(ssqQ[n]), 1e-12f);
    kinv[n] = 1.0f / fmaxf(sqrtf(ssqK[n]), 1e-12f);
  }
  __syncthreads();
  const float sinv_b =
      1.0f / fmaxf(sqrtf(sred[0] + sred[1] + sred[2] + sred[3]), 1e-12f);

  float acc[8] = {};
  const int r0 = b * 4096 + chunk * 128 + wave * 32;
  for (int r = 0; r < 32; r++) {
    const int n = r0 + r;
    float qi = 1.0f / fmaxf(sqrtf(ssqQ[n]), 1e-12f);
    float wrow = P[n] * qi * qi * sinv_b;
    uint4 u = *(const uint4*)(Q + (size_t)n * DD + lane * 8);
    const unsigned short* h = (const unsigned short*)&u;
#pragma unroll
    for (int j = 0; j < 8; j++) acc[j] += wrow * bf2f(h[j]);
  }
#pragma unroll
  for (int j = 0; j < 8; j++) gred[wave][lane * 8 + j] = acc[j];
  __syncthreads();
  float g0 = gred[0][t] + gred[1][t] + gred[2][t] + gred[3][t];
  float g1 = gred[0][t + 256] + gred[1][t + 256] + gred[2][t + 256] + gred[3][t + 256];
  atomicAdd(&G[b * DD + t], g0);
  atomicAdd(&G[b * DD + t + 256], g1);
}

extern "C" void kernel_launch(void* const* d_in, const int* in_sizes, int n_in,
                              void* d_out, int out_size, void* d_ws, size_t ws_size,
                              hipStream_t stream) {
  const float* a   = (const float*)d_in[0];
  const float* b   = (const float*)d_in[1];
  const float* Wq  = (const float*)d_in[2];
  const float* bq  = (const float*)d_in[3];
  const float* Wk  = (const float*)d_in[4];
  const float* bk  = (const float*)d_in[5];
  const float* wg  = (const float*)d_in[6];
  const float* Wp  = (const float*)d_in[7];
  const float* bp  = (const float*)d_in[8];
  const float* Wf  = (const float*)d_in[9];
  const float* bfb = (const float*)d_in[10];

  const size_t WELEM = 262144;          // 512*512
  const size_t MD = (size_t)MTOT * DD;  // 16,777,216 elems

  unsigned short* O1b = (unsigned short*)d_ws;  // O1 intermediate
  unsigned short* Qb  = O1b + MD;               // raw Q (bf16)
  unsigned short* Kb  = Qb + MD;                // raw K (bf16)
  unsigned short* Wqb = Kb + MD;
  unsigned short* Wkb = Wqb + WELEM;
  unsigned short* Wfb = Wkb + WELEM;
  unsigned short* Wps = Wfb + WELEM;            // 8 * 262144 per-batch scaled Wp
  float* stats = (float*)(Wps + 8 * WELEM);
  float* ssqQ  = stats;                 // [MTOT]   zeroed by cvt3w_k
  float* ssqK  = stats + MTOT;          // [MTOT]   zeroed by cvt3w_k
  float* Pd    = stats + 2 * MTOT;      // [MTOT]   zeroed by cvt3w_k
  float* G     = stats + 3 * MTOT;      // [8*512]  zeroed by cvt3w_k
  float* qinv  = G + 4096;
  float* kinv  = qinv + MTOT;

  // weights -> bf16; zero stats+G
  cvt3w_k<<<dim3(868), dim3(256), 0, stream>>>(Wq, Wk, Wf, Wqb, Wkb, Wfb, stats);
  // Q = a*Wq^T+bq (+ssqQ, Pdot); K = b*Wk^T+bk (+ssqK); fp32 A fused cvt
  gemm_qk_k<<<dim3(2048), dim3(256), 0, stream>>>(
      a, b, Wqb, Wkb, bq, bk, wg, ssqQ, ssqK, Pd, Qb, Kb);
  // qinv/kinv + per-batch sinv + learned pooling -> G
  pool2_k<<<dim3(256), dim3(256), 0, stream>>>(ssqQ, ssqK, Pd, qinv, kinv, Qb, G);
  // fold G into Wp per batch
  scalew_k<<<dim3(2048), dim3(256), 0, stream>>>(Wp, G, Wps);
  // O1 = kinv*(Kraw*(Wp.G)^T) + bp + qinv*Qraw
  gemm_k<1, 3><<<dim3(1024), dim3(256), 0, stream>>>(
      Kb, Wps, bp, Qb, qinv, kinv, O1b);
  // out = O1*Wf^T + bf (fp32)
  gemm_k<0, 4><<<dim3(1024), dim3(256), 0, stream>>>(
      O1b, Wfb, bfb, nullptr, nullptr, nullptr, d_out);
}